// Round 3
// baseline (74.208 us; speedup 1.0000x reference)
//
#include <hip/hip_runtime.h>

// YOLO-style loss: pred/target (N, 7, 7, 30) f32 -> 5 scalar losses.
// HBM-streaming reduction. One wave (64 threads) per block; 64-cell tile
// (pred+tgt = 15,360 B LDS) staged via __builtin_amdgcn_global_load_lds
// (direct HBM->LDS, no VGPR round-trip); 10 blocks/CU for latency hiding.
// One thread computes one cell from LDS. No global atomics: per-block
// partials -> d_ws, tiny second kernel reduces.

#define S_GRID 7
#define D_CH   30
#define CELLS_PER_TILE 64
#define T_F4   (CELLS_PER_TILE * D_CH / 4)   // 480 float4 per tensor
#define BOTH_F4 (2 * T_F4)                   // 960 float4 staged (15,360 B)
#define THREADS 64
#define GRID_BLOCKS 2560                     // 10 blocks/CU on 256 CUs

typedef __attribute__((address_space(3))) void       lds_void;
typedef const __attribute__((address_space(1))) void glb_void;

__device__ __forceinline__ void gload_lds16(const float4* g, float4* l) {
    __builtin_amdgcn_global_load_lds((glb_void*)g, (lds_void*)l, 16, 0, 0);
}

__global__ __launch_bounds__(THREADS) void yolo_loss_partial(
    const float* __restrict__ pred, const float* __restrict__ tgt,
    float* __restrict__ ws, int nTiles, long long totalCells)
{
    __shared__ float4 stage[BOTH_F4];   // [0..479] pred tile, [480..959] tgt

    const int lane = threadIdx.x;       // 0..63, single wave
    const float* sp = reinterpret_cast<const float*>(stage);
    const float* st = reinterpret_cast<const float*>(stage + T_F4);

    float lxy = 0.f, lwh = 0.f, lobj = 0.f, lnoobj = 0.f, lcls = 0.f;

    for (int tile = blockIdx.x; tile < nTiles; tile += gridDim.x) {
        const long long cell0 = (long long)tile * CELLS_PER_TILE;
        const float4* gp4 = reinterpret_cast<const float4*>(pred + cell0 * D_CH);
        const float4* gt4 = reinterpret_cast<const float4*>(tgt + cell0 * D_CH);

        __syncthreads();   // previous iteration's LDS reads done before overwrite

        const bool full = (cell0 + CELLS_PER_TILE) <= totalCells;
        if (full) {
            // 15 direct-to-LDS wave loads: LDS dest base uniform per j,
            // HW writes lane*16B; global source per-lane (pred then tgt).
            #pragma unroll
            for (int j = 0; j < 15; ++j) {
                const int k = j * 64 + lane;
                const float4* src = (k < T_F4) ? (gp4 + k) : (gt4 + (k - T_F4));
                gload_lds16(src, &stage[j * 64]);
            }
        } else {
            const long long totalFloats = totalCells * (long long)D_CH;
            const long long baseF = cell0 * (long long)D_CH;
            float* s = reinterpret_cast<float*>(stage);
            for (int f = lane; f < CELLS_PER_TILE * D_CH; f += THREADS) {
                const bool ok = (baseF + f) < totalFloats;
                s[f]             = ok ? pred[baseF + f] : 0.f;
                s[T_F4 * 4 + f]  = ok ? tgt[baseF + f]  : 0.f;
            }
        }
        __syncthreads();   // drains vmcnt(0): global_load_lds complete

        if (cell0 + lane < totalCells) {
            const float* P = sp + lane * D_CH;
            const float* T = st + lane * D_CH;
            const float cellw = 1.0f / (float)S_GRID;

            const float t4 = T[4];
            const float obj   = (t4 == 1.0f) ? 1.0f : 0.0f;
            const float noobj = (t4 == 0.0f) ? 1.0f : 0.0f;

            // target box 0 in ltrb
            const float tlx = T[0] * cellw - T[2] * 0.5f;
            const float tly = T[1] * cellw - T[3] * 0.5f;
            const float trx = T[0] * cellw + T[2] * 0.5f;
            const float tby = T[1] * cellw + T[3] * 0.5f;
            const float area_t = (trx - tlx) * (tby - tly);

            float iou0 = 0.f, iou1 = 0.f;
            #pragma unroll
            for (int b = 0; b < 2; ++b) {
                const float* Pb = P + b * 5;
                const float plx = Pb[0] * cellw - Pb[2] * 0.5f;
                const float ply = Pb[1] * cellw - Pb[3] * 0.5f;
                const float prx = Pb[0] * cellw + Pb[2] * 0.5f;
                const float pby = Pb[1] * cellw + Pb[3] * 0.5f;
                const float ltx = fmaxf(plx, tlx);
                const float lty = fmaxf(ply, tly);
                const float rbx = fminf(prx, trx);
                const float rby = fminf(pby, tby);
                const float wx = fmaxf(rbx - ltx, 0.0f);
                const float wy = fmaxf(rby - lty, 0.0f);
                const float inter = wx * wy;
                const float area_p = (prx - plx) * (pby - ply);
                const float v = inter / (area_p + area_t - inter);
                if (b == 0) iou0 = v; else iou1 = v;
            }

            // argmax first-occurrence tie-break: idx 1 only if strictly greater
            const int bi = (iou1 > iou0) ? 1 : 0;
            const float riou = fmaxf(iou0, iou1);

            const float* Pb = P + bi * 5;
            const float* Tb = T + bi * 5;
            const float dx = Tb[0] - Pb[0];
            const float dy = Tb[1] - Pb[1];
            lxy += obj * (dx * dx + dy * dy);

            const float dw = sqrtf(Tb[2]) - sqrtf(Pb[2]);
            const float dh = sqrtf(Tb[3]) - sqrtf(Pb[3]);
            lwh += obj * (dw * dw + dh * dh);

            const float dc = riou - Pb[4];
            lobj += obj * (dc * dc);

            const float d4 = T[4] - P[4];
            const float d9 = T[9] - P[9];
            lnoobj += noobj * (d4 * d4 + d9 * d9);

            float cs = 0.f;
            #pragma unroll
            for (int c = 10; c < 30; ++c) {
                const float d = T[c] - P[c];
                cs += d * d;
            }
            lcls += obj * cs;
        }
    }

    // ---- single-wave reduction: shuffle tree, lane 0 writes partials
    #pragma unroll
    for (int off = 32; off > 0; off >>= 1) {
        lxy    += __shfl_down(lxy, off);
        lwh    += __shfl_down(lwh, off);
        lobj   += __shfl_down(lobj, off);
        lnoobj += __shfl_down(lnoobj, off);
        lcls   += __shfl_down(lcls, off);
    }
    if (lane == 0) {
        float* p = ws + (long long)blockIdx.x * 5;
        p[0] = lxy; p[1] = lwh; p[2] = lobj; p[3] = lnoobj; p[4] = lcls;
    }
}

__global__ __launch_bounds__(256) void yolo_loss_reduce(
    const float* __restrict__ ws, float* __restrict__ out,
    int nParts, float inv_n)
{
    __shared__ float red[4][5];
    const int tid = threadIdx.x;
    float s0 = 0.f, s1 = 0.f, s2 = 0.f, s3 = 0.f, s4 = 0.f;
    for (int b = tid; b < nParts; b += 256) {
        const float* p = ws + (long long)b * 5;
        s0 += p[0]; s1 += p[1]; s2 += p[2]; s3 += p[3]; s4 += p[4];
    }
    #pragma unroll
    for (int off = 32; off > 0; off >>= 1) {
        s0 += __shfl_down(s0, off);
        s1 += __shfl_down(s1, off);
        s2 += __shfl_down(s2, off);
        s3 += __shfl_down(s3, off);
        s4 += __shfl_down(s4, off);
    }
    const int wave = tid >> 6;
    const int lane = tid & 63;
    if (lane == 0) {
        red[wave][0] = s0; red[wave][1] = s1; red[wave][2] = s2;
        red[wave][3] = s3; red[wave][4] = s4;
    }
    __syncthreads();
    if (tid < 5) {
        float v = 0.f;
        #pragma unroll
        for (int w = 0; w < 4; ++w) v += red[w][tid];
        out[tid] = v * inv_n;
    }
}

extern "C" void kernel_launch(void* const* d_in, const int* in_sizes, int n_in,
                              void* d_out, int out_size, void* d_ws, size_t ws_size,
                              hipStream_t stream) {
    const float* pred = (const float*)d_in[0];
    const float* tgt  = (const float*)d_in[1];
    float* out = (float*)d_out;
    float* ws  = (float*)d_ws;

    const long long totalFloats = (long long)in_sizes[0];
    const long long totalCells = totalFloats / D_CH;                    // N*S*S
    const long long n = totalCells / (S_GRID * S_GRID);                 // N
    const float inv_n = 1.0f / (float)n;

    const int nTiles = (int)((totalCells + CELLS_PER_TILE - 1) / CELLS_PER_TILE);
    const int blocks = (nTiles < GRID_BLOCKS) ? nTiles : GRID_BLOCKS;

    yolo_loss_partial<<<blocks, THREADS, 0, stream>>>(pred, tgt, ws, nTiles, totalCells);
    yolo_loss_reduce<<<1, 256, 0, stream>>>(ws, out, blocks, inv_n);
}